// Round 1
// baseline (1259.895 us; speedup 1.0000x reference)
//
#include <hip/hip_runtime.h>
#include <stdint.h>
#include <stddef.h>

// Problem constants (fixed by setup_inputs).
#define B_ROWS 1024
#define D_DIM  1024
#define N_MEM  100000
#define C_CLS  1000
#define K_TOP  5

// GEMM tiling (m97-style: 128x128 tile, BK=32, 4 waves of 2x2, 16x16x32 MFMA)
#define TM 128
#define TN 128
#define BK 32
#define NT_TILES ((N_MEM + TN - 1) / TN)   // 782
#define BT_TILES (B_ROWS / TM)             // 8
#define NPAD (NT_TILES * TN)               // 100096

typedef __bf16 bf16;
typedef bf16 bf16x4 __attribute__((ext_vector_type(4)));
typedef bf16 bf16x8 __attribute__((ext_vector_type(8)));
typedef float f32x4 __attribute__((ext_vector_type(4)));

// -------------------- K1: normalize rows of features -> bf16 --------------------
__global__ __launch_bounds__(256) void k_normalize(const float* __restrict__ F,
                                                   bf16* __restrict__ X) {
  int row = blockIdx.x;
  int tid = threadIdx.x;
  const float4* fr = (const float4*)(F + (size_t)row * D_DIM);
  float4 v = fr[tid];                     // 256 threads * 4 = 1024 = D
  float s = v.x * v.x + v.y * v.y + v.z * v.z + v.w * v.w;
  for (int off = 32; off > 0; off >>= 1) s += __shfl_down(s, off, 64);
  __shared__ float wred[4];
  if ((tid & 63) == 0) wred[tid >> 6] = s;
  __syncthreads();
  float tot = wred[0] + wred[1] + wred[2] + wred[3];
  float inv = 1.0f / fmaxf(sqrtf(tot), 1e-12f);
  bf16x4 o;
  o[0] = (bf16)(v.x * inv);
  o[1] = (bf16)(v.y * inv);
  o[2] = (bf16)(v.z * inv);
  o[3] = (bf16)(v.w * inv);
  *(bf16x4*)(X + (size_t)row * D_DIM + (size_t)tid * 4) = o;
}

// -------------------- K2: feat_memory fp32 -> bf16 --------------------
__global__ __launch_bounds__(256) void k_convert(const float* __restrict__ FM,
                                                 bf16* __restrict__ FMB, int total4) {
  int i = blockIdx.x * 256 + threadIdx.x;
  if (i >= total4) return;
  float4 v = ((const float4*)FM)[i];
  bf16x4 o;
  o[0] = (bf16)v.x; o[1] = (bf16)v.y; o[2] = (bf16)v.z; o[3] = (bf16)v.w;
  ((bf16x4*)FMB)[i] = o;
}

// -------------------- K3: bf16 MFMA GEMM, dis = X * FMB^T --------------------
__device__ __forceinline__ void gl_lds16(const bf16* g, bf16* l) {
  // async 16B global->LDS; LDS dest must be wave-uniform base + lane*16 (it is).
  __builtin_amdgcn_global_load_lds((__attribute__((address_space(1))) void*)g,
                                   (__attribute__((address_space(3))) void*)l,
                                   16, 0, 0);
}

__global__ __launch_bounds__(256) void k_gemm(const bf16* __restrict__ X,
                                              const bf16* __restrict__ FMB,
                                              bf16* __restrict__ DIS) {
  __shared__ bf16 As[TM * BK];   // 8 KB, row-major [128][32], NO padding (global_load_lds)
  __shared__ bf16 Bs[TN * BK];   // 8 KB
  int bt = blockIdx.x & (BT_TILES - 1);   // b-tile inner -> same-n blocks adjacent (L2 reuse)
  int nt = blockIdx.x >> 3;
  size_t row0 = (size_t)bt * TM;
  size_t col0 = (size_t)nt * TN;
  int tid = threadIdx.x;
  int lane = tid & 63;
  int wv = tid >> 6;
  int wm = wv >> 1, wn = wv & 1;          // 2x2 wave grid, each wave 64x64

  f32x4 acc[4][4];
  for (int mi = 0; mi < 4; ++mi)
    for (int ni = 0; ni < 4; ++ni)
      acc[mi][ni] = (f32x4){0.f, 0.f, 0.f, 0.f};

  int frow = lane & 15;          // A/B fragment row: m (or n) = lane&15
  int kq = (lane >> 4) * 8;      // k offset = quad*8

  const bf16* Xbase = X + row0 * D_DIM;
  const bf16* Fbase = FMB + col0 * D_DIM;

  for (int k0 = 0; k0 < D_DIM; k0 += BK) {
    __syncthreads();
    // stage 128x32 bf16 tiles: 512 chunks of 16B each, 2 rounds of 256 threads
    for (int r = 0; r < 2; ++r) {
      int c = r * 256 + tid;          // 0..511
      int arow = c >> 2;              // 0..127
      int ac = (c & 3) * 8;           // bf16 offset within row
      gl_lds16(Xbase + (size_t)arow * D_DIM + k0 + ac, As + (size_t)c * 8);
      gl_lds16(Fbase + (size_t)arow * D_DIM + k0 + ac, Bs + (size_t)c * 8);
    }
    __syncthreads();   // compiler drains vmcnt before s_barrier

    bf16x8 af[4], bfr[4];
    for (int mi = 0; mi < 4; ++mi)
      af[mi] = *(const bf16x8*)&As[(size_t)(wm * 64 + mi * 16 + frow) * BK + kq];
    for (int ni = 0; ni < 4; ++ni)
      bfr[ni] = *(const bf16x8*)&Bs[(size_t)(wn * 64 + ni * 16 + frow) * BK + kq];
    for (int mi = 0; mi < 4; ++mi)
      for (int ni = 0; ni < 4; ++ni)
        acc[mi][ni] = __builtin_amdgcn_mfma_f32_16x16x32_bf16(af[mi], bfr[ni],
                                                              acc[mi][ni], 0, 0, 0);
  }

  // epilogue: C/D layout col=lane&15, row=(lane>>4)*4+reg  [verified m89/m91]
  int orow = (lane >> 4) * 4;
  int ocol = lane & 15;
  for (int mi = 0; mi < 4; ++mi)
    for (int ni = 0; ni < 4; ++ni)
      for (int r = 0; r < 4; ++r) {
        size_t gr = row0 + (size_t)(wm * 64 + mi * 16 + orow + r);
        size_t gc = col0 + (size_t)(wn * 64 + ni * 16 + ocol);
        DIS[gr * NPAD + gc] = (bf16)acc[mi][ni][r];
      }
}

// -------------------- shared epilogue: gather pred rows, mean, argmax --------------------
__device__ void gather_mean_argmax(const int* find, const float* __restrict__ P,
                                   float* __restrict__ OUT, int b, int tid) {
  float bestV = -1e30f;
  int bestC = 0;
  for (int c = tid; c < C_CLS; c += 256) {
    float s = 0.f;
    for (int j = 0; j < K_TOP; ++j) s += P[(size_t)find[j] * C_CLS + c];
    float mean = s * (1.0f / K_TOP);
    OUT[(size_t)B_ROWS + (size_t)b * C_CLS + c] = mean;
    if (mean > bestV) { bestV = mean; bestC = c; }   // strict > keeps first occurrence
  }
  __shared__ float rv[256];
  __shared__ int rc[256];
  rv[tid] = bestV; rc[tid] = bestC;
  for (int s = 128; s >= 1; s >>= 1) {
    __syncthreads();
    if (tid < s) {
      float v2 = rv[tid + s]; int c2 = rc[tid + s];
      if (v2 > rv[tid] || (v2 == rv[tid] && c2 < rc[tid])) { rv[tid] = v2; rc[tid] = c2; }
    }
  }
  __syncthreads();
  if (tid == 0) OUT[b] = (float)rc[0];   // jnp.argmax: first max index
}

// -------------------- K4: per-row top-5 + epilogue --------------------
__global__ __launch_bounds__(256) void k_topk(const bf16* __restrict__ DIS,
                                              const int* __restrict__ IDX,
                                              const float* __restrict__ P,
                                              float* __restrict__ OUT) {
  int b = blockIdx.x;
  int tid = threadIdx.x;
  int self = IDX[b];
  const bf16* drow = DIS + (size_t)b * NPAD;

  float tv[K_TOP]; int ti[K_TOP];
  for (int j = 0; j < K_TOP; ++j) { tv[j] = -1e30f; ti[j] = 0; }
  for (int n = tid; n < N_MEM; n += 256) {
    if (n == self) continue;      // equivalent to setting dis[b,idx[b]] = global min
    float v = (float)drow[n];
    if (v > tv[K_TOP - 1]) {
      int p = K_TOP - 1;
      while (p > 0 && v > tv[p - 1]) { tv[p] = tv[p - 1]; ti[p] = ti[p - 1]; --p; }
      tv[p] = v; ti[p] = n;
    }
  }
  __shared__ float sv[256 * K_TOP];
  __shared__ int si[256 * K_TOP];
  for (int j = 0; j < K_TOP; ++j) { sv[tid * K_TOP + j] = tv[j]; si[tid * K_TOP + j] = ti[j]; }
  for (int s = 128; s >= 1; s >>= 1) {
    __syncthreads();
    if (tid < s) {
      float av[K_TOP], bv[K_TOP]; int ai[K_TOP], bi[K_TOP];
      for (int j = 0; j < K_TOP; ++j) {
        av[j] = sv[tid * K_TOP + j];       ai[j] = si[tid * K_TOP + j];
        bv[j] = sv[(tid + s) * K_TOP + j]; bi[j] = si[(tid + s) * K_TOP + j];
      }
      float ov[K_TOP]; int oi[K_TOP];
      int i2 = 0, j2 = 0;
      for (int t = 0; t < K_TOP; ++t) {
        if (j2 >= K_TOP || (i2 < K_TOP && av[i2] >= bv[j2])) { ov[t] = av[i2]; oi[t] = ai[i2]; ++i2; }
        else { ov[t] = bv[j2]; oi[t] = bi[j2]; ++j2; }
      }
      for (int j = 0; j < K_TOP; ++j) { sv[tid * K_TOP + j] = ov[j]; si[tid * K_TOP + j] = oi[j]; }
    }
  }
  __syncthreads();
  __shared__ int find[K_TOP];
  if (tid < K_TOP) {
    int v = si[tid];
    find[tid] = (v < 0) ? 0 : (v >= N_MEM ? N_MEM - 1 : v);   // defensive clamp
  }
  __syncthreads();
  gather_mean_argmax(find, P, OUT, b, tid);
}

// -------------------- fallback (only if ws_size too small): slow but ws-free --------------------
__global__ __launch_bounds__(256) void k_naive(const float* __restrict__ F,
                                               const int* __restrict__ IDX,
                                               const float* __restrict__ FM,
                                               const float* __restrict__ P,
                                               float* __restrict__ OUT) {
  int b = blockIdx.x;
  int tid = threadIdx.x;
  __shared__ float xs[D_DIM];
  __shared__ float wred[4];
  const float4* fr = (const float4*)(F + (size_t)b * D_DIM);
  float4 v = fr[tid];
  float s = v.x * v.x + v.y * v.y + v.z * v.z + v.w * v.w;
  for (int off = 32; off > 0; off >>= 1) s += __shfl_down(s, off, 64);
  if ((tid & 63) == 0) wred[tid >> 6] = s;
  __syncthreads();
  float inv = 1.0f / fmaxf(sqrtf(wred[0] + wred[1] + wred[2] + wred[3]), 1e-12f);
  float4 xv = make_float4(v.x * inv, v.y * inv, v.z * inv, v.w * inv);
  ((float4*)xs)[tid] = xv;
  __syncthreads();
  int self = IDX[b];
  __shared__ float ptv[K_TOP];
  __shared__ int pti[K_TOP];
  if (tid < K_TOP) { ptv[tid] = -1e30f; pti[tid] = 0; }
  __syncthreads();
  for (int n = 0; n < N_MEM; ++n) {
    const float4* frow = (const float4*)(FM + (size_t)n * D_DIM);
    float4 fv = frow[tid];
    float p = xv.x * fv.x + xv.y * fv.y + xv.z * fv.z + xv.w * fv.w;
    for (int off = 32; off > 0; off >>= 1) p += __shfl_down(p, off, 64);
    if ((tid & 63) == 0) wred[tid >> 6] = p;
    __syncthreads();
    if (tid == 0 && n != self) {
      float tot = wred[0] + wred[1] + wred[2] + wred[3];
      if (tot > ptv[K_TOP - 1]) {
        int q = K_TOP - 1;
        while (q > 0 && tot > ptv[q - 1]) { ptv[q] = ptv[q - 1]; pti[q] = pti[q - 1]; --q; }
        ptv[q] = tot; pti[q] = n;
      }
    }
    __syncthreads();
  }
  __shared__ int find[K_TOP];
  if (tid < K_TOP) {
    int x = pti[tid];
    find[tid] = (x < 0) ? 0 : (x >= N_MEM ? N_MEM - 1 : x);
  }
  __syncthreads();
  gather_mean_argmax(find, P, OUT, b, tid);
}

// -------------------- launch --------------------
extern "C" void kernel_launch(void* const* d_in, const int* in_sizes, int n_in,
                              void* d_out, int out_size, void* d_ws, size_t ws_size,
                              hipStream_t stream) {
  const float* F  = (const float*)d_in[0];
  const int* IDX  = (const int*)d_in[1];
  const float* FM = (const float*)d_in[2];
  const float* P  = (const float*)d_in[3];
  float* OUT = (float*)d_out;

  const size_t xBytes  = (size_t)B_ROWS * D_DIM * 2;           // 2 MB
  const size_t fmBytes = (size_t)NPAD * D_DIM * 2;             // ~205 MB
  const size_t disBytes = (size_t)B_ROWS * NPAD * 2;           // ~205 MB
  const size_t need = xBytes + fmBytes + disBytes;             // ~412 MB

  if (ws_size >= need) {
    bf16* X   = (bf16*)d_ws;
    bf16* FMB = (bf16*)((char*)d_ws + xBytes);
    bf16* DIS = (bf16*)((char*)d_ws + xBytes + fmBytes);
    k_normalize<<<B_ROWS, 256, 0, stream>>>(F, X);
    int total4 = N_MEM * D_DIM / 4;                            // 25,600,000
    k_convert<<<(total4 + 255) / 256, 256, 0, stream>>>(FM, FMB, total4);
    k_gemm<<<NT_TILES * BT_TILES, 256, 0, stream>>>(X, FMB, DIS);
    k_topk<<<B_ROWS, 256, 0, stream>>>(DIS, IDX, P, OUT);
  } else {
    // diagnostic fallback: correct but slow, needs zero workspace
    k_naive<<<B_ROWS, 256, 0, stream>>>(F, IDX, FM, P, OUT);
  }
}

// Round 2
// 1071.083 us; speedup vs baseline: 1.1763x; 1.1763x over previous
//
#include <hip/hip_runtime.h>
#include <stdint.h>
#include <stddef.h>

// Problem constants (fixed by setup_inputs).
#define B_ROWS 1024
#define D_DIM  1024
#define N_MEM  100000
#define C_CLS  1000
#define K_TOP  5

// GEMM tiling: 128x128 tile, BK=32, 4 waves in 2x2, 16x16x32 MFMA
#define TM 128
#define TN 128
#define BK 32
#define NT_TILES ((N_MEM + TN - 1) / TN)   // 782
#define BT_TILES (B_ROWS / TM)             // 8
#define NPAD (NT_TILES * TN)               // 100096
#define NTL_PER_XCD ((NT_TILES + 7) / 8)   // 98 nt-tiles per XCD (XCD-local L2 reuse)
#define SS_LD (TN + 4)                     // score-tile LDS stride: +4 bf16 kills write conflicts

typedef __bf16 bf16;
typedef bf16 bf16x4 __attribute__((ext_vector_type(4)));
typedef bf16 bf16x8 __attribute__((ext_vector_type(8)));
typedef float f32x4 __attribute__((ext_vector_type(4)));

// sorted-descending top-5 insert, all constant indices (no scratch spill)
__device__ __forceinline__ void insert5(float v, int n, float tv[K_TOP], int ti[K_TOP]) {
#pragma unroll
  for (int j = 0; j < K_TOP; ++j) {
    bool gt = v > tv[j];
    float ov = tv[j]; int oi = ti[j];
    tv[j] = gt ? v : ov;  ti[j] = gt ? n : oi;
    v = gt ? ov : v;      n = gt ? oi : n;
  }
}

// -------------------- K1: normalize rows of features -> bf16 --------------------
__global__ __launch_bounds__(256) void k_normalize(const float* __restrict__ F,
                                                   bf16* __restrict__ X) {
  int row = blockIdx.x;
  int tid = threadIdx.x;
  const float4* fr = (const float4*)(F + (size_t)row * D_DIM);
  float4 v = fr[tid];                     // 256 threads * 4 = 1024 = D
  float s = v.x * v.x + v.y * v.y + v.z * v.z + v.w * v.w;
  for (int off = 32; off > 0; off >>= 1) s += __shfl_down(s, off, 64);
  __shared__ float wred[4];
  if ((tid & 63) == 0) wred[tid >> 6] = s;
  __syncthreads();
  float tot = wred[0] + wred[1] + wred[2] + wred[3];
  float inv = 1.0f / fmaxf(sqrtf(tot), 1e-12f);
  bf16x4 o;
  o[0] = (bf16)(v.x * inv);
  o[1] = (bf16)(v.y * inv);
  o[2] = (bf16)(v.z * inv);
  o[3] = (bf16)(v.w * inv);
  *(bf16x4*)(X + (size_t)row * D_DIM + (size_t)tid * 4) = o;
}

// -------------------- K2: feat_memory fp32 -> bf16 --------------------
__global__ __launch_bounds__(256) void k_convert(const float* __restrict__ FM,
                                                 bf16* __restrict__ FMB, int total4) {
  int i = blockIdx.x * 256 + threadIdx.x;
  if (i >= total4) return;
  float4 v = ((const float4*)FM)[i];
  bf16x4 o;
  o[0] = (bf16)v.x; o[1] = (bf16)v.y; o[2] = (bf16)v.z; o[3] = (bf16)v.w;
  ((bf16x4*)FMB)[i] = o;
}

// -------------------- K3: bf16 MFMA GEMM + per-tile top-5 epilogue --------------------
__device__ __forceinline__ void gl_lds16(const bf16* g, bf16* l) {
  __builtin_amdgcn_global_load_lds((__attribute__((address_space(1))) void*)g,
                                   (__attribute__((address_space(3))) void*)l,
                                   16, 0, 0);
}

__global__ __launch_bounds__(256) void k_gemm_topk(const bf16* __restrict__ X,
                                                   const bf16* __restrict__ FMB,
                                                   const int* __restrict__ IDX,
                                                   float2* __restrict__ CAND) {
  // stage: As/Bs (16 KB), reused as merge buffer in epilogue. Ss: 33.8 KB score tile.
  __shared__ __align__(16) char shm[2 * TM * BK * 2];
  __shared__ bf16 Ss[TM * SS_LD];
  bf16* As = (bf16*)shm;
  bf16* Bs = As + TM * BK;

  int bid = blockIdx.x;
  int xcd = bid & 7;                 // round-robin dispatch heuristic: bid%8 -> XCD
  int rest = bid >> 3;
  int bt = rest & 7;                 // bt varies fastest within an XCD
  int ntl = rest >> 3;
  int nt = xcd * NTL_PER_XCD + ntl;  // each XCD owns a contiguous nt range
  if (nt >= NT_TILES) return;        // uniform early-out, no barriers skipped

  size_t row0 = (size_t)bt * TM;
  size_t col0 = (size_t)nt * TN;
  int tid = threadIdx.x;
  int lane = tid & 63;
  int wv = tid >> 6;
  int wm = wv >> 1, wn = wv & 1;     // 2x2 wave grid, each wave 64x64

  f32x4 acc[4][4];
  for (int mi = 0; mi < 4; ++mi)
    for (int ni = 0; ni < 4; ++ni)
      acc[mi][ni] = (f32x4){0.f, 0.f, 0.f, 0.f};

  int frow = lane & 15;              // A/B fragment row
  int q = lane >> 4;                 // k-quad (16B chunk index within BK row)

  const bf16* Xbase = X + row0 * D_DIM;
  const bf16* Fbase = FMB + col0 * D_DIM;

  for (int k0 = 0; k0 < D_DIM; k0 += BK) {
    __syncthreads();
    // stage 128x32 tiles: 512 16B chunks; XOR-swizzle chunk-within-row by (row>>1)&3
    // so quad reads spread over all 32 banks (2-way aliasing = free, m136).
    for (int r = 0; r < 2; ++r) {
      int c = r * 256 + tid;            // LDS slot 0..511 (dest fixed: base + lane*16)
      int arow = c >> 2;
      int j = (c & 3) ^ ((arow >> 1) & 3);  // which global chunk lands in this slot
      gl_lds16(Xbase + (size_t)arow * D_DIM + k0 + j * 8, As + (size_t)c * 8);
      gl_lds16(Fbase + (size_t)arow * D_DIM + k0 + j * 8, Bs + (size_t)c * 8);
    }
    __syncthreads();

    bf16x8 af[4], bfr[4];
    for (int mi = 0; mi < 4; ++mi) {
      int r = wm * 64 + mi * 16 + frow;
      int slot = r * 4 + (q ^ ((r >> 1) & 3));
      af[mi] = *(const bf16x8*)&As[(size_t)slot * 8];
    }
    for (int ni = 0; ni < 4; ++ni) {
      int r = wn * 64 + ni * 16 + frow;
      int slot = r * 4 + (q ^ ((r >> 1) & 3));
      bfr[ni] = *(const bf16x8*)&Bs[(size_t)slot * 8];
    }
    for (int mi = 0; mi < 4; ++mi)
      for (int ni = 0; ni < 4; ++ni)
        acc[mi][ni] = __builtin_amdgcn_mfma_f32_16x16x32_bf16(af[mi], bfr[ni],
                                                              acc[mi][ni], 0, 0, 0);
  }

  // ---- epilogue 1: scores -> LDS (C/D layout col=lane&15, row=(lane>>4)*4+reg) ----
  int orow = (lane >> 4) * 4;
  int ocol = lane & 15;
  for (int mi = 0; mi < 4; ++mi)
    for (int ni = 0; ni < 4; ++ni)
      for (int r = 0; r < 4; ++r)
        Ss[(size_t)(wm * 64 + mi * 16 + orow + r) * SS_LD + (wn * 64 + ni * 16 + ocol)]
            = (bf16)acc[mi][ni][r];
  __syncthreads();

  // ---- epilogue 2: per-row top-5 within this 128-col tile (2 threads/row) ----
  int tr = tid >> 1, h = tid & 1;
  int grow = (int)row0 + tr;
  int self = IDX[grow];
  float tv[K_TOP]; int ti[K_TOP];
  for (int j = 0; j < K_TOP; ++j) { tv[j] = -1e30f; ti[j] = -1; }
  for (int c = 0; c < 64; ++c) {
    int cc = h * 64 + c;
    int gc = (int)col0 + cc;
    if (gc >= N_MEM || gc == self) continue;   // self-mask == set-to-min trick
    float v = (float)Ss[(size_t)tr * SS_LD + cc];
    if (v > tv[K_TOP - 1]) insert5(v, gc, tv, ti);
  }

  // merge the two halves via LDS (aliased onto As/Bs stage; all stage reads done)
  float* mv = (float*)shm;                       // 256*5*4 = 5120 B
  int* mi_ = (int*)(shm + 8192);                 // 5120 B
  for (int j = 0; j < K_TOP; ++j) { mv[tid * K_TOP + j] = tv[j]; mi_[tid * K_TOP + j] = ti[j]; }
  __syncthreads();
  if (h == 0) {
    for (int j = 0; j < K_TOP; ++j) {
      float v = mv[(tid + 1) * K_TOP + j];
      int n = mi_[(tid + 1) * K_TOP + j];
      if (v > tv[K_TOP - 1]) insert5(v, n, tv, ti);
    }
    float2* out = CAND + ((size_t)grow * NT_TILES + nt) * K_TOP;
    for (int j = 0; j < K_TOP; ++j)
      out[j] = make_float2(tv[j], __int_as_float(ti[j]));
  }
}

// -------------------- shared epilogue: gather pred rows, mean, argmax --------------------
__device__ void gather_mean_argmax(const int* find, const float* __restrict__ P,
                                   float* __restrict__ OUT, int b, int tid) {
  float bestV = -1e30f;
  int bestC = 0;
  for (int c = tid; c < C_CLS; c += 256) {
    float s = 0.f;
    for (int j = 0; j < K_TOP; ++j) s += P[(size_t)find[j] * C_CLS + c];
    float mean = s * (1.0f / K_TOP);
    OUT[(size_t)B_ROWS + (size_t)b * C_CLS + c] = mean;
    if (mean > bestV) { bestV = mean; bestC = c; }   // strict > keeps first occurrence
  }
  __shared__ float rv[256];
  __shared__ int rc[256];
  rv[tid] = bestV; rc[tid] = bestC;
  for (int s = 128; s >= 1; s >>= 1) {
    __syncthreads();
    if (tid < s) {
      float v2 = rv[tid + s]; int c2 = rc[tid + s];
      if (v2 > rv[tid] || (v2 == rv[tid] && c2 < rc[tid])) { rv[tid] = v2; rc[tid] = c2; }
    }
  }
  __syncthreads();
  if (tid == 0) OUT[b] = (float)rc[0];   // jnp.argmax: first max index
}

// -------------------- K4: merge per-tile candidates -> global top-5 + epilogue ------
__global__ __launch_bounds__(256) void k_merge(const float2* __restrict__ CAND,
                                               const float* __restrict__ P,
                                               float* __restrict__ OUT) {
  int b = blockIdx.x;
  int tid = threadIdx.x;
  const float2* row = CAND + (size_t)b * (NT_TILES * K_TOP);

  float tv[K_TOP]; int ti[K_TOP];
  for (int j = 0; j < K_TOP; ++j) { tv[j] = -1e30f; ti[j] = -1; }
  for (int i = tid; i < NT_TILES * K_TOP; i += 256) {
    float2 e = row[i];
    float v = e.x;
    if (v > tv[K_TOP - 1]) insert5(v, __float_as_int(e.y), tv, ti);
  }

  __shared__ float sv[256 * K_TOP];
  __shared__ int si[256 * K_TOP];
  for (int j = 0; j < K_TOP; ++j) { sv[tid * K_TOP + j] = tv[j]; si[tid * K_TOP + j] = ti[j]; }
  for (int s = 128; s >= 1; s >>= 1) {
    __syncthreads();
    if (tid < s) {
      for (int j = 0; j < K_TOP; ++j) {
        float v = sv[(tid + s) * K_TOP + j];
        int n = si[(tid + s) * K_TOP + j];
        if (v > tv[K_TOP - 1]) insert5(v, n, tv, ti);
      }
      for (int j = 0; j < K_TOP; ++j) { sv[tid * K_TOP + j] = tv[j]; si[tid * K_TOP + j] = ti[j]; }
    }
  }
  __syncthreads();
  __shared__ int find[K_TOP];
  if (tid == 0)
    for (int j = 0; j < K_TOP; ++j) {
      int v = si[j];
      find[j] = (v < 0) ? 0 : (v >= N_MEM ? N_MEM - 1 : v);   // defensive clamp
    }
  __syncthreads();
  gather_mean_argmax(find, P, OUT, b, tid);
}

// -------------------- fallback (only if ws_size too small): slow but ws-free --------
__global__ __launch_bounds__(256) void k_naive(const float* __restrict__ F,
                                               const int* __restrict__ IDX,
                                               const float* __restrict__ FM,
                                               const float* __restrict__ P,
                                               float* __restrict__ OUT) {
  int b = blockIdx.x;
  int tid = threadIdx.x;
  __shared__ float wred[4];
  const float4* fr = (const float4*)(F + (size_t)b * D_DIM);
  float4 v = fr[tid];
  float s = v.x * v.x + v.y * v.y + v.z * v.z + v.w * v.w;
  for (int off = 32; off > 0; off >>= 1) s += __shfl_down(s, off, 64);
  if ((tid & 63) == 0) wred[tid >> 6] = s;
  __syncthreads();
  float inv = 1.0f / fmaxf(sqrtf(wred[0] + wred[1] + wred[2] + wred[3]), 1e-12f);
  float4 xv = make_float4(v.x * inv, v.y * inv, v.z * inv, v.w * inv);
  __syncthreads();
  int self = IDX[b];
  __shared__ float ptv[K_TOP];
  __shared__ int pti[K_TOP];
  if (tid < K_TOP) { ptv[tid] = -1e30f; pti[tid] = 0; }
  __syncthreads();
  for (int n = 0; n < N_MEM; ++n) {
    const float4* frow = (const float4*)(FM + (size_t)n * D_DIM);
    float4 fv = frow[tid];
    float p = xv.x * fv.x + xv.y * fv.y + xv.z * fv.z + xv.w * fv.w;
    for (int off = 32; off > 0; off >>= 1) p += __shfl_down(p, off, 64);
    if ((tid & 63) == 0) wred[tid >> 6] = p;
    __syncthreads();
    if (tid == 0 && n != self) {
      float tot = wred[0] + wred[1] + wred[2] + wred[3];
      if (tot > ptv[K_TOP - 1]) {
        int q = K_TOP - 1;
        while (q > 0 && tot > ptv[q - 1]) { ptv[q] = ptv[q - 1]; pti[q] = pti[q - 1]; --q; }
        ptv[q] = tot; pti[q] = n;
      }
    }
    __syncthreads();
  }
  __shared__ int find[K_TOP];
  if (tid < K_TOP) {
    int x = pti[tid];
    find[tid] = (x < 0) ? 0 : (x >= N_MEM ? N_MEM - 1 : x);
  }
  __syncthreads();
  gather_mean_argmax(find, P, OUT, b, tid);
}

// -------------------- launch --------------------
extern "C" void kernel_launch(void* const* d_in, const int* in_sizes, int n_in,
                              void* d_out, int out_size, void* d_ws, size_t ws_size,
                              hipStream_t stream) {
  const float* F  = (const float*)d_in[0];
  const int* IDX  = (const int*)d_in[1];
  const float* FM = (const float*)d_in[2];
  const float* P  = (const float*)d_in[3];
  float* OUT = (float*)d_out;

  const size_t xBytes    = (size_t)B_ROWS * D_DIM * 2;                 // 2 MB
  const size_t fmBytes   = (size_t)NPAD * D_DIM * 2;                   // ~205 MB
  const size_t candBytes = (size_t)B_ROWS * NT_TILES * K_TOP * 8;      // ~32 MB
  const size_t need = xBytes + fmBytes + candBytes;                    // ~239 MB

  if (ws_size >= need) {
    bf16* X      = (bf16*)d_ws;
    bf16* FMB    = (bf16*)((char*)d_ws + xBytes);
    float2* CAND = (float2*)((char*)d_ws + xBytes + fmBytes);
    k_normalize<<<B_ROWS, 256, 0, stream>>>(F, X);
    int total4 = N_MEM * D_DIM / 4;                                    // 25,600,000
    k_convert<<<(total4 + 255) / 256, 256, 0, stream>>>(FM, FMB, total4);
    k_gemm_topk<<<8 * NTL_PER_XCD * BT_TILES, 256, 0, stream>>>(X, FMB, IDX, CAND);
    k_merge<<<B_ROWS, 256, 0, stream>>>(CAND, P, OUT);
  } else {
    // diagnostic fallback: correct but slow, needs zero workspace
    k_naive<<<B_ROWS, 256, 0, stream>>>(F, IDX, FM, P, OUT);
  }
}